// Round 1
// baseline (140.117 us; speedup 1.0000x reference)
//
#include <hip/hip_runtime.h>

#define B_ 32
#define M_ 4096
#define M1_ 4097
#define H_ 32
#define D_ 4096

typedef float float4_ __attribute__((ext_vector_type(4)));
typedef float f32x4 __attribute__((ext_vector_type(4)));
typedef short short8 __attribute__((ext_vector_type(8)));

#define KOFF 131072
#define VOFF 16912384
// ws layout (f32 elements)
#define QPART_OFF 0u           // 16*34*32*128 = 2228224
#define Q_OFF     2228224u     // 34*32*128    = 139264
#define APART_OFF 2367488u     // 32*32*32*132 = 4325376
#define O_OFF     6692864u     // 32*32*128    = 131072
#define YPART_OFF 6823936u     // 8*131072     = 1048576  -> total 7872512 f32 (31.5 MB)

__device__ __forceinline__ unsigned short f2bf(float f) {
  union { float f; unsigned u; } cv; cv.f = f;
  return (unsigned short)((cv.u + 0x7FFFu + ((cv.u >> 16) & 1u)) >> 16);
}

__device__ __forceinline__ short8 pack8(const float* t) {
  short8 r;
#pragma unroll
  for (int j = 0; j < 8; ++j) r[j] = (short)f2bf(t[j]);
  return r;
}

__device__ __forceinline__ short8 load8cvt(const float* __restrict__ p) {
  float t[8];
  float4_ v0 = *(const float4_*)p;
  float4_ v1 = *(const float4_*)(p + 4);
#pragma unroll
  for (int j = 0; j < 4; ++j) { t[j] = v0[j]; t[4 + j] = v1[j]; }
  return pack8(t);
}

// ---------------- kernel 1: projections (q per head, k_new, v_new), split-D partials
// grid = 34 heads * 16 d-chunks = 544 blocks, 256 threads.
// "head" 32 -> P_k, 33 -> P_v.
__global__ __launch_bounds__(256) void k_proj(const float* __restrict__ x,
    const float* __restrict__ Pq, const float* __restrict__ Pk,
    const float* __restrict__ Pv, float* __restrict__ qpart)
{
  int bid = blockIdx.x;
  int hh = bid >> 4;
  int c  = bid & 15;
  const float* W = (hh < 32) ? (Pq + (size_t)hh * D_ * 128)
                             : ((hh == 32) ? Pk : Pv);
  int d0 = c * 256;
  int tid = threadIdx.x;
  int w = tid >> 6, l = tid & 63, l15 = l & 15, lg = l >> 4;
  f32x4 acc[2][2] = {};          // [b-tile][n-tile]
  for (int ks = 0; ks < 8; ++ks) {
    int dk = d0 + ks * 32 + lg * 8;
    short8 af[2];
#pragma unroll
    for (int bt = 0; bt < 2; ++bt)
      af[bt] = load8cvt(x + (size_t)(bt * 16 + l15) * D_ + dk);
    short8 bf[2];
#pragma unroll
    for (int nti = 0; nti < 2; ++nti) {
      int col = (2 * w + nti) * 16 + l15;
      float t[8];
#pragma unroll
      for (int j = 0; j < 8; ++j) t[j] = W[(size_t)(dk + j) * 128 + col];
      bf[nti] = pack8(t);
    }
#pragma unroll
    for (int bt = 0; bt < 2; ++bt)
#pragma unroll
      for (int nti = 0; nti < 2; ++nti)
        acc[bt][nti] = __builtin_amdgcn_mfma_f32_16x16x32_bf16(af[bt], bf[nti], acc[bt][nti], 0, 0, 0);
  }
#pragma unroll
  for (int bt = 0; bt < 2; ++bt)
#pragma unroll
    for (int nti = 0; nti < 2; ++nti) {
      int k = (2 * w + nti) * 16 + l15;
#pragma unroll
      for (int i = 0; i < 4; ++i) {
        int b = bt * 16 + lg * 4 + i;
        qpart[(size_t)((c * 34 + hh) * 32 + b) * 128 + k] = acc[bt][nti][i];
      }
    }
}

// ---------------- kernel 2: reduce projection partials; write new K/V cache row
__global__ __launch_bounds__(256) void k_reduce_q(const float* __restrict__ qpart,
    float* __restrict__ q, float* __restrict__ dout)
{
  int idx = blockIdx.x * 256 + threadIdx.x;   // 34*32*128 = 139264
  if (idx >= 34 * 32 * 128) return;
  float s = 0.f;
#pragma unroll
  for (int cc = 0; cc < 16; ++cc) s += qpart[(size_t)cc * 139264 + idx];
  q[idx] = s;
  int hh = idx >> 12;
  if (hh >= 32) {
    int b = (idx >> 7) & 31, k = idx & 127;
    size_t off = (hh == 32) ? (size_t)KOFF : (size_t)VOFF;
    dout[off + ((size_t)b * M1_ + M_) * 128 + k] = s;
  }
}

// ---------------- kernel 3: fused cache copy + flash-attention partials
// grid = B * 32 chunks = 1024 blocks (exactly 4/CU), 256 threads.
__global__ __launch_bounds__(256) void k_attn(const float* __restrict__ Kp,
    const float* __restrict__ Vp, const float* __restrict__ q,
    float* __restrict__ dout, float* __restrict__ apart)
{
  __shared__ float S[32][136];
  __shared__ unsigned short P[32][128];
  __shared__ float smax[32], ssum[32], sextra[32];
  int bid = blockIdx.x;
  int b = bid >> 5, c = bid & 31;
  int m0 = c * 128;
  int tid = threadIdx.x, w = tid >> 6, l = tid & 63, l15 = l & 15, lg = l >> 4;
  const float* Kt = Kp + ((size_t)b * M_ + m0) * 128;
  const float* Vt = Vp + ((size_t)b * M_ + m0) * 128;
  float* Kn = dout + KOFF + ((size_t)b * M1_ + m0) * 128;
  float* Vn = dout + VOFF + ((size_t)b * M1_ + m0) * 128;

  // phase A: copy K tile (f32, coalesced); leaves tile L2-warm for frag reads
#pragma unroll
  for (int i = 0; i < 16; ++i) {
    int idx = tid + i * 256;
    ((float4_*)Kn)[idx] = ((const float4_*)Kt)[idx];
  }

  // phase B: S[h][m] = q . K^T  (bf16 MFMA, frags straight from global/L2)
  f32x4 sacc[2][2] = {};
#pragma unroll
  for (int ks = 0; ks < 4; ++ks) {
    short8 af[2], bf[2];
#pragma unroll
    for (int ht = 0; ht < 2; ++ht) {
      int h = ht * 16 + l15;
      af[ht] = load8cvt(q + (size_t)(h * 32 + b) * 128 + ks * 32 + lg * 8);
    }
#pragma unroll
    for (int mti = 0; mti < 2; ++mti) {
      int m = (2 * w + mti) * 16 + l15;
      bf[mti] = load8cvt(Kt + (size_t)m * 128 + ks * 32 + lg * 8);
    }
#pragma unroll
    for (int ht = 0; ht < 2; ++ht)
#pragma unroll
      for (int mti = 0; mti < 2; ++mti)
        sacc[ht][mti] = __builtin_amdgcn_mfma_f32_16x16x32_bf16(af[ht], bf[mti], sacc[ht][mti], 0, 0, 0);
  }
#pragma unroll
  for (int ht = 0; ht < 2; ++ht)
#pragma unroll
    for (int mti = 0; mti < 2; ++mti)
#pragma unroll
      for (int i = 0; i < 4; ++i)
        S[ht * 16 + lg * 4 + i][(2 * w + mti) * 16 + l15] = sacc[ht][mti][i];

  // appended-token logit (exact f32), chunk 31 only
  if (c == 31 && tid < 32) {
    int h = tid;
    const float* qh = q + (size_t)(h * 32 + b) * 128;
    const float* kn = q + (size_t)(32 * 32 + b) * 128;
    float s = 0.f;
    for (int k = 0; k < 128; ++k) s += qh[k] * kn[k];
    S[h][128] = s;
  }
  __syncthreads();

  // phase C: per-head partial softmax (8 lanes per head)
  {
    int h = tid >> 3, i = tid & 7;
    float vals[16];
    float mx = -1e30f;
#pragma unroll
    for (int j = 0; j < 16; ++j) { vals[j] = S[h][i * 16 + j]; mx = fmaxf(mx, vals[j]); }
#pragma unroll
    for (int d = 1; d < 8; d <<= 1) mx = fmaxf(mx, __shfl_xor(mx, d));
    if (c == 31) mx = fmaxf(mx, S[h][128]);
    float se = 0.f;
#pragma unroll
    for (int j = 0; j < 16; ++j) {
      float p = __expf(vals[j] - mx);
      se += p;
      P[h][(i * 16 + j) ^ ((h & 7) << 3)] = f2bf(p);   // XOR swizzle vs bank conflicts
    }
    if (c == 31 && i == 0) { float pe = __expf(S[h][128] - mx); se += pe; sextra[h] = pe; }
#pragma unroll
    for (int d = 1; d < 8; d <<= 1) se += __shfl_xor(se, d);
    if (i == 0) { smax[h] = mx; ssum[h] = se; }
  }
  __syncthreads();

  // phase D: copy V tile (leaves it L2-warm for PV frags)
#pragma unroll
  for (int i = 0; i < 16; ++i) {
    int idx = tid + i * 256;
    ((float4_*)Vn)[idx] = ((const float4_*)Vt)[idx];
  }

  // phase E: O[h][v] = P x V (P from LDS swizzled, V frags strided from L2)
  f32x4 oacc[2][2] = {};
#pragma unroll
  for (int ks = 0; ks < 4; ++ks) {
    short8 af[2], bf[2];
#pragma unroll
    for (int ht = 0; ht < 2; ++ht) {
      int h = ht * 16 + l15;
      int mb = (ks * 32 + lg * 8) ^ ((h & 7) << 3);
      af[ht] = *(const short8*)&P[h][mb];
    }
#pragma unroll
    for (int vti = 0; vti < 2; ++vti) {
      int v = (2 * w + vti) * 16 + l15;
      float t[8];
#pragma unroll
      for (int j = 0; j < 8; ++j) t[j] = Vt[(size_t)(ks * 32 + lg * 8 + j) * 128 + v];
      bf[vti] = pack8(t);
    }
#pragma unroll
    for (int ht = 0; ht < 2; ++ht)
#pragma unroll
      for (int vti = 0; vti < 2; ++vti)
        oacc[ht][vti] = __builtin_amdgcn_mfma_f32_16x16x32_bf16(af[ht], bf[vti], oacc[ht][vti], 0, 0, 0);
  }

  // phase F: write per-chunk partials (unnormalized o, local max, local sumexp)
  const float* vnew = q + (size_t)(33 * 32 + b) * 128;
#pragma unroll
  for (int ht = 0; ht < 2; ++ht)
#pragma unroll
    for (int vti = 0; vti < 2; ++vti) {
      int v = (2 * w + vti) * 16 + l15;
#pragma unroll
      for (int i = 0; i < 4; ++i) {
        int h = ht * 16 + lg * 4 + i;
        float val = oacc[ht][vti][i];
        if (c == 31) val += sextra[h] * vnew[v];
        apart[((size_t)((b * 32 + c) * 32 + h)) * 132 + v] = val;
      }
    }
  if (tid < 32) {
    apart[((size_t)((b * 32 + c) * 32 + tid)) * 132 + 128] = smax[tid];
    apart[((size_t)((b * 32 + c) * 32 + tid)) * 132 + 129] = ssum[tid];
  }
}

// ---------------- kernel 4: combine chunk partials -> o[b][h][v]
__global__ void k_combine(const float* __restrict__ apart, float* __restrict__ o)
{
  int bid = blockIdx.x;            // 1024: b*32+h
  int b = bid >> 5, h = bid & 31;
  int v = threadIdx.x;             // 128
  const float* base = apart + ((size_t)(b * 32) * 32 + h) * 132;
  float gm = -1e30f;
  for (int cc = 0; cc < 32; ++cc) gm = fmaxf(gm, base[(size_t)cc * 32 * 132 + 128]);
  float num = 0.f, den = 0.f;
  for (int cc = 0; cc < 32; ++cc) {
    const float* pc = base + (size_t)cc * 32 * 132;
    float sc = __expf(pc[128] - gm);
    num += sc * pc[v];
    den += sc * pc[129];
  }
  o[((size_t)(b * 32 + h)) * 128 + v] = num / den;
}

// ---------------- kernel 5: y partials = o x P_o  (grid 256 = 32 d-tiles x 8 head-groups)
__global__ __launch_bounds__(256) void k_out(const float* __restrict__ o,
    const float* __restrict__ Po, float* __restrict__ ypart)
{
  int bid = blockIdx.x;
  int dt = bid >> 3, hg = bid & 7;
  int tid = threadIdx.x, w = tid >> 6, l = tid & 63, l15 = l & 15, lg = l >> 4;
  f32x4 acc[2][2] = {};            // [b-tile][d-subtile]
  for (int hi = 0; hi < 4; ++hi) {
    int h = hg * 4 + hi;
#pragma unroll
    for (int ks = 0; ks < 4; ++ks) {
      short8 af[2], bf[2];
#pragma unroll
      for (int bt = 0; bt < 2; ++bt)
        af[bt] = load8cvt(o + ((size_t)((bt * 16 + l15) * 32 + h)) * 128 + ks * 32 + lg * 8);
#pragma unroll
      for (int dtl = 0; dtl < 2; ++dtl) {
        int d = dt * 128 + (2 * w + dtl) * 16 + l15;
        bf[dtl] = load8cvt(Po + ((size_t)h * D_ + d) * 128 + ks * 32 + lg * 8);
      }
#pragma unroll
      for (int bt = 0; bt < 2; ++bt)
#pragma unroll
        for (int dtl = 0; dtl < 2; ++dtl)
          acc[bt][dtl] = __builtin_amdgcn_mfma_f32_16x16x32_bf16(af[bt], bf[dtl], acc[bt][dtl], 0, 0, 0);
    }
  }
#pragma unroll
  for (int bt = 0; bt < 2; ++bt)
#pragma unroll
    for (int dtl = 0; dtl < 2; ++dtl) {
      int d = dt * 128 + (2 * w + dtl) * 16 + l15;
#pragma unroll
      for (int i = 0; i < 4; ++i) {
        int b = bt * 16 + lg * 4 + i;
        ypart[((size_t)(hg * 32 + b)) * 4096 + d] = acc[bt][dtl][i];
      }
    }
}

// ---------------- kernel 6: reduce y partials -> y
__global__ __launch_bounds__(256) void k_reduce_y(const float* __restrict__ ypart,
    float* __restrict__ dout)
{
  int idx = blockIdx.x * 256 + threadIdx.x;  // 131072
  float s = 0.f;
#pragma unroll
  for (int g = 0; g < 8; ++g) s += ypart[(size_t)g * 131072 + idx];
  dout[idx] = s;
}

extern "C" void kernel_launch(void* const* d_in, const int* in_sizes, int n_in,
                              void* d_out, int out_size, void* d_ws, size_t ws_size,
                              hipStream_t stream) {
  (void)in_sizes; (void)n_in; (void)out_size; (void)ws_size;
  const float* x  = (const float*)d_in[0];
  const float* Kp = (const float*)d_in[1];
  const float* Vp = (const float*)d_in[2];
  const float* Pq = (const float*)d_in[3];
  const float* Pk = (const float*)d_in[4];
  const float* Pv = (const float*)d_in[5];
  const float* Po = (const float*)d_in[6];
  float* out = (float*)d_out;
  float* ws  = (float*)d_ws;
  float* qpart = ws + QPART_OFF;
  float* q     = ws + Q_OFF;
  float* apart = ws + APART_OFF;
  float* o     = ws + O_OFF;
  float* ypart = ws + YPART_OFF;

  hipLaunchKernelGGL(k_proj,     dim3(544),  dim3(256), 0, stream, x, Pq, Pk, Pv, qpart);
  hipLaunchKernelGGL(k_reduce_q, dim3(544),  dim3(256), 0, stream, qpart, q, out);
  hipLaunchKernelGGL(k_attn,     dim3(1024), dim3(256), 0, stream, Kp, Vp, q, out, apart);
  hipLaunchKernelGGL(k_combine,  dim3(1024), dim3(128), 0, stream, apart, o);
  hipLaunchKernelGGL(k_out,      dim3(256),  dim3(256), 0, stream, o, Po, ypart);
  hipLaunchKernelGGL(k_reduce_y, dim3(512),  dim3(256), 0, stream, ypart, out);
}